// Round 11
// baseline (283.185 us; speedup 1.0000x reference)
//
#include <hip/hip_runtime.h>

using bf16x8 = __attribute__((ext_vector_type(8))) short;
using f32x4  = __attribute__((ext_vector_type(4))) float;

#define B_  2
#define T_  2048
#define C_  2048
#define H_  16
#define KV_ 4
#define D_  128

__device__ __forceinline__ unsigned short f2b(float f) {
  union { float f; unsigned int u; } v; v.f = f;
  unsigned int r = v.u + 0x7fffu + ((v.u >> 16) & 1u);   // RTNE
  return (unsigned short)(r >> 16);
}
__device__ __forceinline__ float b2f(unsigned short u) {
  union { unsigned int u; float f; } v; v.u = ((unsigned int)u) << 16;
  return v.f;
}
// packed f32x2 -> bf16x2 (RTNE), single VALU op (no gfx950 builtin; T12 recipe)
__device__ __forceinline__ unsigned int cvt_pk_bf16(float lo, float hi) {
  unsigned int r;
  asm("v_cvt_pk_bf16_f32 %0, %1, %2" : "=v"(r) : "v"(lo), "v"(hi));
  return r;
}
// async global->LDS, 16B per lane; LDS dest must be lane-contiguous (wave base + lane*16)
__device__ __forceinline__ void gld_lds16(const void* g, void* l) {
  __builtin_amdgcn_global_load_lds(
      (__attribute__((address_space(1))) void*)g,
      (__attribute__((address_space(3))) void*)l, 16, 0, 0);
}

// ------------- prep: x cast (8192 blocks) + 4x weight transpose (10240 blocks) -------------
__global__ void prep(const float* __restrict__ x, unsigned short* __restrict__ xb,
                     const float* __restrict__ Wq, const float* __restrict__ Wk,
                     const float* __restrict__ Wv, const float* __restrict__ Wo,
                     unsigned short* __restrict__ Wqt, unsigned short* __restrict__ Wkt,
                     unsigned short* __restrict__ Wvt, unsigned short* __restrict__ Wot) {
  __shared__ float s[32][33];
  int bid = blockIdx.x, tid = threadIdx.x;
  if (bid < 8192) {                          // cast x -> bf16
    int i = bid * 256 + tid;
    float4 f = ((const float4*)x)[i];
    ushort4 u; u.x = f2b(f.x); u.y = f2b(f.y); u.z = f2b(f.z); u.w = f2b(f.w);
    ((ushort4*)xb)[i] = u;
    return;
  }
  int id = bid - 8192;
  const float* W; unsigned short* Wt; int N;
  if (id < 4096)      { W = Wq; Wt = Wqt; N = 2048; }
  else if (id < 5120) { W = Wk; Wt = Wkt; N = 512;  id -= 4096; }
  else if (id < 6144) { W = Wv; Wt = Wvt; N = 512;  id -= 5120; }
  else                { W = Wo; Wt = Wot; N = 2048; id -= 6144; }
  int ntiles = N >> 5;
  int n0 = (id % ntiles) * 32, k0 = (id / ntiles) * 32;
  int tx = tid & 31, ty = tid >> 5;
  #pragma unroll
  for (int yy = 0; yy < 32; yy += 8)
    s[ty + yy][tx] = W[(size_t)(k0 + ty + yy) * N + n0 + tx];
  __syncthreads();
  #pragma unroll
  for (int yy = 0; yy < 32; yy += 8)
    Wt[(size_t)(n0 + ty + yy) * 2048 + k0 + tx] = f2b(s[tx][ty + yy]);
}

// ------------- qkv GEMM (R7/R9-verified, 56us): fused-N 256x192, 2-phase, XOR swizzle -------
// R8 ERRATA: fragment-order LDS (0 conflicts) REGRESSED to 80us — global_load_lds dest
// is lane-contiguous, so frag-order LDS forces uncoalesced global staging. Keep
// row-segment staging + 2-bit XOR swizzle (residual 4-way conflict = known ~8.5us tax).
// R10 ERRATA: fusing Q RoPE+RMSNorm into attn REGRESSED attn 56->81us (scattered Q loads
// + serial prep chain at phase start, barrier-locked at 1 block/CU = pure stall).
__global__ __launch_bounds__(512, 2) void qkv_gemm2p(
    const unsigned short* __restrict__ xb,
    const unsigned short* __restrict__ Wt,      // 3072 x 2048 (Q|K|V rows)
    unsigned short* __restrict__ qkv) {         // 4096 x 3072
  __shared__ unsigned short lds[57344];         // A: 32768 sh ; B at +32768: 24576 sh

  const int id  = (int)blockIdx.x;              // 0..255; id&7 = XCD (round-robin)
  const int xcd = id & 7, j = id >> 3;          // 32 blocks per XCD
  const int mt  = xcd * 2 + (j >> 4);           // each XCD owns 2 A-panels (L2-resident)
  const int nt  = j & 15;
  const int m0 = mt * 256, n0 = nt * 192;

  const int tid = (int)threadIdx.x;
  const int w = tid >> 6, lane = tid & 63;
  const int quad = lane >> 4, l16 = lane & 15;
  const int wr = w >> 1, wc = w & 1;            // wave tile: rows wr*64, cols wc*96
  const int swz = (l16 & 12) << 1;              // ((row>>2)&3)<<3 in shorts

  const unsigned short* Ab = xb + (size_t)m0 * 2048;
  const unsigned short* Bb = Wt + (size_t)n0 * 2048;

  int ar[4], axc[4];
  #pragma unroll
  for (int kq = 0; kq < 4; ++kq) {
    int ca = tid + kq * 512;
    ar[kq]  = (ca & 1023) >> 2;
    axc[kq] = ((ca & 3) * 8) ^ ((((ca & 1023) >> 4) & 3) << 3);   // inverse-swizzled src col
  }
  const int khb1 = (tid < 256) ? 0 : 1;
  int bidx[3] = { tid, tid + 512 - khb1 * 768, tid + 256 };
  int bkh[3]  = { 0, khb1, 1 };
  int br[3], bxc[3];
  #pragma unroll
  for (int kq = 0; kq < 3; ++kq) {
    br[kq]  = bidx[kq] >> 2;
    bxc[kq] = ((bidx[kq] & 3) * 8) ^ (((bidx[kq] >> 4) & 3) << 3);
  }

#define STAGE(buf, kb) do { \
    unsigned short* da_ = lds + (buf) * 16384; \
    _Pragma("unroll") \
    for (int kq = 0; kq < 4; ++kq) { \
      int ca_ = tid + kq * 512; \
      gld_lds16(Ab + (size_t)ar[kq] * 2048 + (kb) + (ca_ >> 10) * 32 + axc[kq], da_ + ca_ * 8); \
    } \
    unsigned short* db_ = lds + 32768 + (buf) * 12288; \
    _Pragma("unroll") \
    for (int kq = 0; kq < 3; ++kq) \
      gld_lds16(Bb + (size_t)br[kq] * 2048 + (kb) + bkh[kq] * 32 + bxc[kq], \
                db_ + bkh[kq] * 6144 + bidx[kq] * 8); \
  } while (0)

  f32x4 acc[4][6] = {};

  STAGE(0, 0);
  __syncthreads();

  const unsigned short* aB = lds + (wr * 64 + l16) * 32 + (quad * 8 ^ swz);
  const unsigned short* bB = lds + 32768 + (wc * 96 + l16) * 32 + (quad * 8 ^ swz);

  for (int t = 0; t < 32; ++t) {
    const int cur = t & 1;
    if (t < 31) STAGE(cur ^ 1, (t + 1) * 64);   // issue first; reads+MFMA hide it
    #pragma unroll
    for (int kh = 0; kh < 2; ++kh) {
      bf16x8 a[4], b[6];
      #pragma unroll
      for (int m = 0; m < 4; ++m)
        a[m] = *(const bf16x8*)(aB + cur * 16384 + kh * 8192 + m * 512);
      #pragma unroll
      for (int n = 0; n < 6; ++n)
        b[n] = *(const bf16x8*)(bB + cur * 12288 + kh * 6144 + n * 512);
      #pragma unroll
      for (int m = 0; m < 4; ++m)
        #pragma unroll
        for (int n = 0; n < 6; ++n)
          acc[m][n] = __builtin_amdgcn_mfma_f32_16x16x32_bf16(a[m], b[n], acc[m][n], 0, 0, 0);
    }
    __syncthreads();    // vmcnt(0)+lgkm(0)+barrier: stage had full-iter lead -> cheap
  }
#undef STAGE

  #pragma unroll
  for (int m = 0; m < 4; ++m)
    #pragma unroll
    for (int r = 0; r < 4; ++r) {
      int row = m0 + wr * 64 + m * 16 + quad * 4 + r;
      #pragma unroll
      for (int n = 0; n < 6; ++n) {
        int col = n0 + wc * 96 + n * 16 + l16;
        qkv[(size_t)row * 3072 + col] = f2b(acc[m][n][r]);
      }
    }
}

// ------------- out GEMM (R7/R9-verified): 256x128 tile, 2-phase, XOR swizzle -------------
__global__ __launch_bounds__(512, 2) void out_gemm2p(
    const unsigned short* __restrict__ yb,      // 4096 x 2048 bf16
    const unsigned short* __restrict__ Wot,     // 2048 x 2048 bf16 (N x K)
    float* __restrict__ out) {                  // 4096 x 2048 fp32
  __shared__ unsigned short lds[49152];         // A: 32768 sh ; B at +32768: 16384 sh

  const int id  = (int)blockIdx.x;              // 0..255
  const int xcd = id & 7, j = id >> 3;
  const int mt  = xcd * 2 + (j >> 4);
  const int nt  = j & 15;
  const int m0 = mt * 256, n0 = nt * 128;

  const int tid = (int)threadIdx.x;
  const int w = tid >> 6, lane = tid & 63;
  const int quad = lane >> 4, l16 = lane & 15;
  const int wr = w >> 1, wc = w & 1;            // wave tile: rows wr*64, cols wc*64
  const int swz = (l16 & 12) << 1;

  const unsigned short* Ab = yb  + (size_t)m0 * 2048;
  const unsigned short* Bb = Wot + (size_t)n0 * 2048;

  int ar[4], axc[4];                            // A: 2048 chunks, 4/thread
  #pragma unroll
  for (int kq = 0; kq < 4; ++kq) {
    int ca = tid + kq * 512;
    ar[kq]  = (ca & 1023) >> 2;
    axc[kq] = ((ca & 3) * 8) ^ ((((ca & 1023) >> 4) & 3) << 3);
  }
  int brr[2], bxc[2];                           // B: 1024 chunks, 2/thread (kh = kq)
  #pragma unroll
  for (int kq = 0; kq < 2; ++kq) {
    int cb = tid + kq * 512;
    brr[kq] = (cb & 511) >> 2;
    bxc[kq] = ((cb & 3) * 8) ^ ((((cb & 511) >> 4) & 3) << 3);
  }

#define STAGE(buf, kb) do { \
    unsigned short* da_ = lds + (buf) * 16384; \
    _Pragma("unroll") \
    for (int kq = 0; kq < 4; ++kq) { \
      int ca_ = tid + kq * 512; \
      gld_lds16(Ab + (size_t)ar[kq] * 2048 + (kb) + (ca_ >> 10) * 32 + axc[kq], da_ + ca_ * 8); \
    } \
    unsigned short* db_ = lds + 32768 + (buf) * 8192; \
    _Pragma("unroll") \
    for (int kq = 0; kq < 2; ++kq) { \
      int cb_ = tid + kq * 512; \
      gld_lds16(Bb + (size_t)brr[kq] * 2048 + (kb) + kq * 32 + bxc[kq], db_ + cb_ * 8); \
    } \
  } while (0)

  f32x4 acc[4][4] = {};

  STAGE(0, 0);
  __syncthreads();

  const unsigned short* aB = lds + (wr * 64 + l16) * 32 + (quad * 8 ^ swz);
  const unsigned short* bB = lds + 32768 + (wc * 64 + l16) * 32 + (quad * 8 ^ swz);

  for (int t = 0; t < 32; ++t) {
    const int cur = t & 1;
    if (t < 31) STAGE(cur ^ 1, (t + 1) * 64);
    #pragma unroll
    for (int kh = 0; kh < 2; ++kh) {
      bf16x8 a[4], b[4];
      #pragma unroll
      for (int m = 0; m < 4; ++m)
        a[m] = *(const bf16x8*)(aB + cur * 16384 + kh * 8192 + m * 512);
      #pragma unroll
      for (int n = 0; n < 4; ++n)
        b[n] = *(const bf16x8*)(bB + cur * 8192 + kh * 4096 + n * 512);
      #pragma unroll
      for (int m = 0; m < 4; ++m)
        #pragma unroll
        for (int n = 0; n < 4; ++n)
          acc[m][n] = __builtin_amdgcn_mfma_f32_16x16x32_bf16(a[m], b[n], acc[m][n], 0, 0, 0);
    }
    __syncthreads();
  }
#undef STAGE

  #pragma unroll
  for (int m = 0; m < 4; ++m)
    #pragma unroll
    for (int r = 0; r < 4; ++r) {
      int row = m0 + wr * 64 + m * 16 + quad * 4 + r;
      #pragma unroll
      for (int n = 0; n < 4; ++n) {
        int col = n0 + wc * 64 + n * 16 + l16;
        out[(size_t)row * 2048 + col] = acc[m][n][r];
      }
    }
}

// ---------------- RoPE + RMSNorm row helper ----------------
template <int NH>
__device__ __forceinline__ void ropenorm_row(
    const unsigned short* __restrict__ in, const float* __restrict__ cs,
    const float* __restrict__ sn, unsigned short* __restrict__ out,
    float oscale, int off, int row, int lane) {
  int head = row % NH;
  int t = (row / NH) & (T_ - 1);
  int b = row / (NH * T_);
  const unsigned short* p = in + (size_t)(b * T_ + t) * 3072 + off + head * D_;
  unsigned int u  = *(const unsigned int*)(p + 2 * lane);
  unsigned int up = (unsigned int)__shfl_xor((int)u, 32, 64);
  int dh = (lane & 31) * 2;
  float2 c2 = ((const float2*)(cs + t * 64))[lane & 31];
  float2 s2 = ((const float2*)(sn + t * 64))[lane & 31];
  float a0 = b2f((unsigned short)(u & 0xffff)),  a1 = b2f((unsigned short)(u >> 16));
  float p0 = b2f((unsigned short)(up & 0xffff)), p1 = b2f((unsigned short)(up >> 16));
  float sgn = (lane < 32) ? 1.0f : -1.0f;
  float oa = a0 * c2.x + sgn * p0 * s2.x;
  float ob = a1 * c2.y + sgn * p1 * s2.y;
  float ss = oa * oa + ob * ob;
  #pragma unroll
  for (int off2 = 32; off2 > 0; off2 >>= 1) ss += __shfl_xor(ss, off2, 64);
  float r = rsqrtf(ss * (1.0f / 128.0f) + 1.1920929e-07f) * oscale;
  unsigned int outu = cvt_pk_bf16(oa * r, ob * r);
  size_t base = ((size_t)((b * NH + head) * 128 + (t >> 4))) * 2048 + (size_t)(t & 15) * 8;
  int f = ((lane < 32) ? 0 : 8) + (dh >> 3);
  *(unsigned int*)(out + base + (size_t)f * 128 + (dh & 7)) = outu;
}

// ------- post: RoPE+RMSNorm for Q (16384 blk) + K (4096 blk) + V repack (256 blk) -------
__global__ void post_k(const unsigned short* __restrict__ qkv,
                       const float* __restrict__ cs, const float* __restrict__ sn,
                       unsigned short* __restrict__ qfr, unsigned short* __restrict__ kfr,
                       unsigned short* __restrict__ vf) {
  int bid = blockIdx.x, tid = threadIdx.x;
  int lane = tid & 63, wv = tid >> 6;
  if (bid < 16384) {
    ropenorm_row<16>(qkv, cs, sn, qfr, 0.08838834764831845f, 0, bid * 4 + wv, lane);
    return;
  }
  if (bid < 20480) {
    ropenorm_row<4>(qkv, cs, sn, kfr, 1.0f, 2048, (bid - 16384) * 4 + wv, lane);
    return;
  }
  // V repack: per (b,kv): [it 32][dt = d>>4 (8)][f (8)][d&15 (16)][t&7 (8)]
  int id = bid - 20480;                      // 0..255
  int it = id & 31, y = id >> 5;
  int b = y >> 2, kv = y & 3;
  int d = tid & 127, ty = tid >> 7;
  int t0 = it * 64;
  size_t obase = ((size_t)((b * KV_ + kv) * 32 + it)) * 8192
               + (size_t)(d >> 4) * 1024 + (size_t)(d & 15) * 8;
  #pragma unroll
  for (int tcg = 0; tcg < 4; ++tcg) {
    int tc = ty * 4 + tcg;                   // f chunk 0..7
    unsigned short val[8];
    #pragma unroll
    for (int e = 0; e < 8; ++e)              // coalesced: 128 lanes contiguous in d
      val[e] = qkv[((size_t)(b * T_) + t0 + tc * 8 + e) * 3072 + 2560 + kv * D_ + d];
    ushort4 u0 = {val[0], val[1], val[2], val[3]};
    ushort4 u1 = {val[4], val[5], val[6], val[7]};
    *(ushort4*)(vf + obase + (size_t)tc * 128)     = u0;
    *(ushort4*)(vf + obase + (size_t)tc * 128 + 4) = u1;
  }
}

// ------------ flash attention v11: head-shared LDS K/V staging, uniform blocks ------------
// (verified R6/R7/R9: 56us.) Block = 8 waves = 4 heads x 2 kv-halves; qt = j then 63-j;
// K/V staged once per kv-group via global_load_lds (L2 traffic /4); counted vmcnt;
// XOR-swizzled K/V reads; static max M=12 -> halves combine linearly.
__global__ __launch_bounds__(512, 2) void attn_kernel(
    const unsigned short* __restrict__ qf, const unsigned short* __restrict__ kf,
    const unsigned short* __restrict__ vf, unsigned short* __restrict__ yb) {
  __shared__ __align__(16) char smem[135168];
  unsigned short* kls = (unsigned short*)smem;            // [2 buf][2 slot][8192 sh]
  unsigned short* vls = (unsigned short*)(smem + 65536);  // [2 slot][8192 sh]
  unsigned short* Pls = (unsigned short*)(smem + 98304);  // 8 waves x 32x72 sh

  const int xp = (int)blockIdx.x, b = xp >> 2, kv = xp & 3;   // XCD swizzle: id%8 = xp
  const int jy = (int)blockIdx.y;                             // 0..31
  const int tid = (int)threadIdx.x;
  const int w = tid >> 6, lane = tid & 63;
  const int quad = lane >> 4, l16 = lane & 15;
  const int hh = w & 3, half = w >> 2;
  const int h = kv * 4 + hh;
  unsigned short* myP = Pls + w * (32 * 72);

  const unsigned short* Kf = kf + (size_t)(b * KV_ + kv) * 128 * 2048;
  const unsigned short* Vf = vf + (size_t)(b * KV_ + kv) * 32 * 8192;

  const int swl = quad << 4;                 // swizzle key (shorts): chunk ^ (quad<<1)
  const int cs0 = (tid * 8) ^ swl;           // staging source offsets within a 16KB tile
  const int cs1 = ((tid + 512) * 8) ^ swl;
  const int cd0 = tid * 8, cd1 = tid * 8 + 4096;   // linear LDS dest (lane-contiguous)

#define STAGE_K(buf, it0) do { \
    const unsigned short* s_ = Kf + (size_t)(it0) * 8192; \
    unsigned short* d_ = kls + (buf) * 16384; \
    gld_lds16(s_ + cs0, d_ + cd0);               gld_lds16(s_ + cs1, d_ + cd1); \
    gld_lds16(s_ + 8192 + cs0, d_ + 8192 + cd0); gld_lds16(s_ + 8192 + cs1, d_ + 8192 + cd1); \
  } while (0)
#define STAGE_V(it0) do { \
    const unsigned short* s_ = Vf + (size_t)(it0) * 8192; \
    gld_lds16(s_ + cs0, vls + cd0);               gld_lds16(s_ + cs1, vls + cd1); \
    gld_lds16(s_ + 8192 + cs0, vls + 8192 + cd0); gld_lds16(s_ + 8192 + cs1, vls + 8192 + cd1); \
  } while (0)

  for (int ph = 0; ph < 2; ++ph) {
    const int qt = ph ? (63 - jy) : jy;
    const int q0 = qt * 32;
    const int ntile = (qt >> 1) + 1;
    const int R = (ntile + 1) >> 1;

    const unsigned short* Qf = qf + ((size_t)(b * H_ + h) * 128 + qt * 2) * 2048;
    bf16x8 bq[2][4];
    #pragma unroll
    for (int i = 0; i < 2; ++i)
      #pragma unroll
      for (int kk = 0; kk < 4; ++kk)
        bq[i][kk] = *(const bf16x8*)(Qf + (size_t)i * 2048 + (kk * 4 + quad) * 128 + l16 * 8);

    float l_i[2] = {0.f, 0.f};
    f32x4 o[2][8] = {};

    STAGE_K(0, 0);                           // prologue: K tiles 0,1 -> buf 0

    for (int r = 0; r < R; ++r) {
      const int cur = r & 1;
      const bool more = (r + 1 < R);
      STAGE_V(2 * r);
      if (more) STAGE_K(cur ^ 1, 2 * r + 2);
      if (more) asm volatile("s_waitcnt vmcnt(8)" ::: "memory");  // K(2r,2r+1) landed (own)
      else      asm volatile("s_waitcnt vmcnt(4)" ::: "memory");
      __builtin_amdgcn_s_barrier();                               // ...and globally

      const int it = 2 * r + half;
      const bool active = it < ntile;        // wave-uniform
      f32x4 sc[4][2] = {};
      if (active) {
        const unsigned short* kb = kls + cur * 16384 + half * 8192;
        #pragma unroll
        for (int kk = 0; kk < 4; ++kk) {
          bf16x8 ak[4];
          #pragma unroll
          for (int jt = 0; jt < 4; ++jt)
            ak[jt] = *(const bf16x8*)(kb + ((jt * 2048 + (kk * 4 + quad) * 128 + l16 * 8) ^ swl));
          #pragma unroll
          for (int jt = 0; jt < 4; ++jt)
            #pragma unroll
            for (int i = 0; i < 2; ++i)
              sc[jt][i] = __builtin_amdgcn_mfma_f32_16x16x32_bf16(ak[jt], bq[i][kk], sc[jt][i], 0, 0, 0);
        }
        if (it == ntile - 1) {               // causal mask on the diagonal tile
          #pragma unroll
          for (int jt = 0; jt < 4; ++jt) {
            int kg = it * 64 + jt * 16 + quad * 4;
            #pragma unroll
            for (int i = 0; i < 2; ++i) {
              int qg = q0 + i * 16 + l16;
              #pragma unroll
              for (int rr = 0; rr < 4; ++rr)
                if (kg + rr > qg) sc[jt][i][rr] = -3.0e38f;
            }
          }
        }
        #pragma unroll
        for (int i = 0; i < 2; ++i) {
          float part = 0.f;
          #pragma unroll
          for (int jt = 0; jt < 4; ++jt)
            #pragma unroll
            for (int rr = 0; rr < 4; ++rr) {
              float p = __expf(sc[jt][i][rr] - 12.0f);
              sc[jt][i][rr] = p; part += p;
            }
          l_i[i] += part;
        }
        #pragma unroll
        for (int i = 0; i < 2; ++i)
          #pragma unroll
          for (int jt = 0; jt < 4; ++jt) {
            uint2 uu;
            uu.x = cvt_pk_bf16(sc[jt][i][0], sc[jt][i][1]);
            uu.y = cvt_pk_bf16(sc[jt][i][2], sc[jt][i][3]);
            *(uint2*)(myP + (i * 16 + l16) * 72 + jt * 16 + quad * 4) = uu;
          }
      }

      if (more) asm volatile("s_waitcnt vmcnt(4)" ::: "memory");  // V(2r,2r+1) landed
      else      asm volatile("s_waitcnt vmcnt(0)" ::: "memory");
      __builtin_amdgcn_s_barrier();

      if (active) {
        const unsigned short* vb = vls + half * 8192;
        #pragma unroll
        for (int kk2 = 0; kk2 < 2; ++kk2) {
          bf16x8 ap[2], bv2[8];
          #pragma unroll
          for (int i = 0; i < 2; ++i)
            ap[i] = *(const bf16x8*)(myP + (i * 16 + l16) * 72 + kk2 * 32 + quad * 8);
          #pragma unroll
          for (int jj = 0; jj < 8; ++jj)
            bv2[jj] = *(const bf16x8*)(vb + ((jj * 1024 + (kk2 * 4 + quad) * 128 + l16 * 8) ^ swl));
          #pragma unroll
          for (int i = 0; i < 2; ++i)
            #pragma unroll
            for (int jj = 0; jj < 8; ++jj)
              o[i][jj] = __builtin_amdgcn_mfma_f32_16x16x32_bf16(ap[i], bv2[jj], o[i][jj], 0, 0, 0);
        }
      }
      __builtin_amdgcn_s_barrier();          // all PV reads done before next STAGE_V
    }

    float lsum[2];
    #pragma unroll
    for (int i = 0; i < 2; ++i) {
      float l = l_i[i];
      l += __shfl_xor(l, 16, 64);
      l += __shfl_xor(l, 32, 64);
      lsum[i] = l;
    }

    __syncthreads();                         // rounds done; kls/vls dead -> combine scratch
    float* oc = (float*)smem + hh * 4256;    // per head: 32x132 o + 32 l floats
    float* lc = oc + 32 * 132;
    if (half == 1) {
      #pragma unroll
      for (int i = 0; i < 2; ++i) {
        if (quad == 0) lc[i * 16 + l16] = lsum[i];
        #pragma unroll
        for (int jj = 0; jj < 8; ++jj)
          #pragma unroll
          for (int rr = 0; rr < 4; ++rr)
            oc[(i * 16 + quad * 4 + rr) * 132 + jj * 16 + l16] = o[i][jj][rr];
      }
    }
    __syncthreads();
    if (half == 0) {                         // linear combine (static max) + store
      #pragma unroll
      for (int i = 0; i < 2; ++i) {
        float l = lsum[i] + lc[i * 16 + l16];
        float linv = 1.0f / l;
        float lr[4];
        #pragma unroll
        for (int rr = 0; rr < 4; ++rr) lr[rr] = __shfl(linv, quad * 4 + rr, 64);
        #pragma unroll
        for (int rr = 0; rr < 4; ++rr) {
          int tg = q0 + i * 16 + quad * 4 + rr;
          unsigned short* yr = yb + (((size_t)(b * T_ + tg)) * H_ + h) * D_;
          #pragma unroll
          for (int jj = 0; jj < 8; ++jj) {
            float vsum = o[i][jj][rr] + oc[(i * 16 + quad * 4 + rr) * 132 + jj * 16 + l16];
            yr[jj * 16 + l16] = f2b(vsum * lr[rr]);
          }
        }
      }
    }
    __syncthreads();                         // scratch reads done before next phase stages
  }
#undef STAGE_K
#undef STAGE_V
}

extern "C" void kernel_launch(void* const* d_in, const int* in_sizes, int n_in,
                              void* d_out, int out_size, void* d_ws, size_t ws_size,
                              hipStream_t stream) {
  (void)in_sizes; (void)n_in; (void)out_size; (void)ws_size;
  const float* x  = (const float*)d_in[0];
  const float* cs = (const float*)d_in[1];
  const float* sn = (const float*)d_in[2];
  const float* Wq = (const float*)d_in[3];
  const float* Wk = (const float*)d_in[4];
  const float* Wv = (const float*)d_in[5];
  const float* Wo = (const float*)d_in[6];
  float* out = (float*)d_out;
  char* ws = (char*)d_ws;

  // workspace layout (bytes); regions reused across phases. total ~88MB.
  unsigned short* xb     = (unsigned short*)(ws + 0);          // 4096x2048 bf16 (dead after qkv)
  unsigned short* Wqkvt  = (unsigned short*)(ws + 16777216);   // 3072x2048 bf16 (dead after qkv)
  unsigned short* Wot    = (unsigned short*)(ws + 29360128);   // needed until out_gemm
  unsigned short* qkvcat = (unsigned short*)(ws + 37748736);   // 4096x3072 bf16 fused Q|K|V
  unsigned short* qfr    = (unsigned short*)(ws + 62914560);   // Q frag order
  unsigned short* kfr    = (unsigned short*)(ws + 79691776);   // K frag order
  unsigned short* vfr    = (unsigned short*)(ws + 83886080);   // V frag order
  unsigned short* yb     = xb;                                 // attn out (B,T,C) bf16 (xb dead)

  prep<<<dim3(18432), dim3(256), 0, stream>>>(
      x, xb, Wq, Wk, Wv, Wo,
      Wqkvt, Wqkvt + (size_t)2048 * 2048, Wqkvt + (size_t)2560 * 2048, Wot);
  qkv_gemm2p<<<dim3(256), dim3(512), 0, stream>>>(xb, Wqkvt, qkvcat);
  post_k<<<dim3(20736), dim3(256), 0, stream>>>(qkvcat, cs, sn, qfr, kfr, vfr);
  attn_kernel<<<dim3(8, 32), dim3(512), 0, stream>>>(qfr, kfr, vfr, yb);
  out_gemm2p<<<dim3(256), dim3(512), 0, stream>>>(yb, Wot, out);
}

// Round 12
// 278.036 us; speedup vs baseline: 1.0185x; 1.0185x over previous
//
#include <hip/hip_runtime.h>

using bf16x8 = __attribute__((ext_vector_type(8))) short;
using f32x4  = __attribute__((ext_vector_type(4))) float;

#define B_  2
#define T_  2048
#define C_  2048
#define H_  16
#define KV_ 4
#define D_  128

__device__ __forceinline__ unsigned short f2b(float f) {
  union { float f; unsigned int u; } v; v.f = f;
  unsigned int r = v.u + 0x7fffu + ((v.u >> 16) & 1u);   // RTNE
  return (unsigned short)(r >> 16);
}
__device__ __forceinline__ float b2f(unsigned short u) {
  union { unsigned int u; float f; } v; v.u = ((unsigned int)u) << 16;
  return v.f;
}
// packed f32x2 -> bf16x2 (RTNE), single VALU op (no gfx950 builtin; T12 recipe)
__device__ __forceinline__ unsigned int cvt_pk_bf16(float lo, float hi) {
  unsigned int r;
  asm("v_cvt_pk_bf16_f32 %0, %1, %2" : "=v"(r) : "v"(lo), "v"(hi));
  return r;
}
// async global->LDS, 16B per lane; LDS dest must be lane-contiguous (wave base + lane*16)
__device__ __forceinline__ void gld_lds16(const void* g, void* l) {
  __builtin_amdgcn_global_load_lds(
      (__attribute__((address_space(1))) void*)g,
      (__attribute__((address_space(3))) void*)l, 16, 0, 0);
}

// ------------- prep: x cast (8192 blocks) + 4x weight transpose (10240 blocks) -------------
__global__ void prep(const float* __restrict__ x, unsigned short* __restrict__ xb,
                     const float* __restrict__ Wq, const float* __restrict__ Wk,
                     const float* __restrict__ Wv, const float* __restrict__ Wo,
                     unsigned short* __restrict__ Wqt, unsigned short* __restrict__ Wkt,
                     unsigned short* __restrict__ Wvt, unsigned short* __restrict__ Wot) {
  __shared__ float s[32][33];
  int bid = blockIdx.x, tid = threadIdx.x;
  if (bid < 8192) {                          // cast x -> bf16
    int i = bid * 256 + tid;
    float4 f = ((const float4*)x)[i];
    ushort4 u; u.x = f2b(f.x); u.y = f2b(f.y); u.z = f2b(f.z); u.w = f2b(f.w);
    ((ushort4*)xb)[i] = u;
    return;
  }
  int id = bid - 8192;
  const float* W; unsigned short* Wt; int N;
  if (id < 4096)      { W = Wq; Wt = Wqt; N = 2048; }
  else if (id < 5120) { W = Wk; Wt = Wkt; N = 512;  id -= 4096; }
  else if (id < 6144) { W = Wv; Wt = Wvt; N = 512;  id -= 5120; }
  else                { W = Wo; Wt = Wot; N = 2048; id -= 6144; }
  int ntiles = N >> 5;
  int n0 = (id % ntiles) * 32, k0 = (id / ntiles) * 32;
  int tx = tid & 31, ty = tid >> 5;
  #pragma unroll
  for (int yy = 0; yy < 32; yy += 8)
    s[ty + yy][tx] = W[(size_t)(k0 + ty + yy) * N + n0 + tx];
  __syncthreads();
  #pragma unroll
  for (int yy = 0; yy < 32; yy += 8)
    Wt[(size_t)(n0 + ty + yy) * 2048 + k0 + tx] = f2b(s[tx][ty + yy]);
}

// ------------- qkv GEMM (R7/R9-verified, 56us): fused-N 256x192, 2-phase, XOR swizzle -------
// At the ~880 TF plain-HIP 2-phase ceiling (m131-m141); 8-phase ports regressed twice.
// R8 ERRATA: fragment-order LDS (0 conflicts) regressed (uncoalesced staging).
__global__ __launch_bounds__(512, 2) void qkv_gemm2p(
    const unsigned short* __restrict__ xb,
    const unsigned short* __restrict__ Wt,      // 3072 x 2048 (Q|K|V rows)
    unsigned short* __restrict__ qkv) {         // 4096 x 3072
  __shared__ unsigned short lds[57344];         // A: 32768 sh ; B at +32768: 24576 sh

  const int id  = (int)blockIdx.x;              // 0..255; id&7 = XCD (round-robin)
  const int xcd = id & 7, j = id >> 3;          // 32 blocks per XCD
  const int mt  = xcd * 2 + (j >> 4);           // each XCD owns 2 A-panels (L2-resident)
  const int nt  = j & 15;
  const int m0 = mt * 256, n0 = nt * 192;

  const int tid = (int)threadIdx.x;
  const int w = tid >> 6, lane = tid & 63;
  const int quad = lane >> 4, l16 = lane & 15;
  const int wr = w >> 1, wc = w & 1;            // wave tile: rows wr*64, cols wc*96
  const int swz = (l16 & 12) << 1;              // ((row>>2)&3)<<3 in shorts

  const unsigned short* Ab = xb + (size_t)m0 * 2048;
  const unsigned short* Bb = Wt + (size_t)n0 * 2048;

  int ar[4], axc[4];
  #pragma unroll
  for (int kq = 0; kq < 4; ++kq) {
    int ca = tid + kq * 512;
    ar[kq]  = (ca & 1023) >> 2;
    axc[kq] = ((ca & 3) * 8) ^ ((((ca & 1023) >> 4) & 3) << 3);   // inverse-swizzled src col
  }
  const int khb1 = (tid < 256) ? 0 : 1;
  int bidx[3] = { tid, tid + 512 - khb1 * 768, tid + 256 };
  int bkh[3]  = { 0, khb1, 1 };
  int br[3], bxc[3];
  #pragma unroll
  for (int kq = 0; kq < 3; ++kq) {
    br[kq]  = bidx[kq] >> 2;
    bxc[kq] = ((bidx[kq] & 3) * 8) ^ (((bidx[kq] >> 4) & 3) << 3);
  }

#define STAGE(buf, kb) do { \
    unsigned short* da_ = lds + (buf) * 16384; \
    _Pragma("unroll") \
    for (int kq = 0; kq < 4; ++kq) { \
      int ca_ = tid + kq * 512; \
      gld_lds16(Ab + (size_t)ar[kq] * 2048 + (kb) + (ca_ >> 10) * 32 + axc[kq], da_ + ca_ * 8); \
    } \
    unsigned short* db_ = lds + 32768 + (buf) * 12288; \
    _Pragma("unroll") \
    for (int kq = 0; kq < 3; ++kq) \
      gld_lds16(Bb + (size_t)br[kq] * 2048 + (kb) + bkh[kq] * 32 + bxc[kq], \
                db_ + bkh[kq] * 6144 + bidx[kq] * 8); \
  } while (0)

  f32x4 acc[4][6] = {};

  STAGE(0, 0);
  __syncthreads();

  const unsigned short* aB = lds + (wr * 64 + l16) * 32 + (quad * 8 ^ swz);
  const unsigned short* bB = lds + 32768 + (wc * 96 + l16) * 32 + (quad * 8 ^ swz);

  for (int t = 0; t < 32; ++t) {
    const int cur = t & 1;
    if (t < 31) STAGE(cur ^ 1, (t + 1) * 64);   // issue first; reads+MFMA hide it
    #pragma unroll
    for (int kh = 0; kh < 2; ++kh) {
      bf16x8 a[4], b[6];
      #pragma unroll
      for (int m = 0; m < 4; ++m)
        a[m] = *(const bf16x8*)(aB + cur * 16384 + kh * 8192 + m * 512);
      #pragma unroll
      for (int n = 0; n < 6; ++n)
        b[n] = *(const bf16x8*)(bB + cur * 12288 + kh * 6144 + n * 512);
      #pragma unroll
      for (int m = 0; m < 4; ++m)
        #pragma unroll
        for (int n = 0; n < 6; ++n)
          acc[m][n] = __builtin_amdgcn_mfma_f32_16x16x32_bf16(a[m], b[n], acc[m][n], 0, 0, 0);
    }
    __syncthreads();    // vmcnt(0)+lgkm(0)+barrier: stage had full-iter lead -> cheap
  }
#undef STAGE

  #pragma unroll
  for (int m = 0; m < 4; ++m)
    #pragma unroll
    for (int r = 0; r < 4; ++r) {
      int row = m0 + wr * 64 + m * 16 + quad * 4 + r;
      #pragma unroll
      for (int n = 0; n < 6; ++n) {
        int col = n0 + wc * 96 + n * 16 + l16;
        qkv[(size_t)row * 3072 + col] = f2b(acc[m][n][r]);
      }
    }
}

// ------------- out GEMM (R7/R9-verified): 256x128 tile, 2-phase, XOR swizzle -------------
__global__ __launch_bounds__(512, 2) void out_gemm2p(
    const unsigned short* __restrict__ yb,      // 4096 x 2048 bf16
    const unsigned short* __restrict__ Wot,     // 2048 x 2048 bf16 (N x K)
    float* __restrict__ out) {                  // 4096 x 2048 fp32
  __shared__ unsigned short lds[49152];         // A: 32768 sh ; B at +32768: 16384 sh

  const int id  = (int)blockIdx.x;              // 0..255
  const int xcd = id & 7, j = id >> 3;
  const int mt  = xcd * 2 + (j >> 4);
  const int nt  = j & 15;
  const int m0 = mt * 256, n0 = nt * 128;

  const int tid = (int)threadIdx.x;
  const int w = tid >> 6, lane = tid & 63;
  const int quad = lane >> 4, l16 = lane & 15;
  const int wr = w >> 1, wc = w & 1;            // wave tile: rows wr*64, cols wc*64
  const int swz = (l16 & 12) << 1;

  const unsigned short* Ab = yb  + (size_t)m0 * 2048;
  const unsigned short* Bb = Wot + (size_t)n0 * 2048;

  int ar[4], axc[4];                            // A: 2048 chunks, 4/thread
  #pragma unroll
  for (int kq = 0; kq < 4; ++kq) {
    int ca = tid + kq * 512;
    ar[kq]  = (ca & 1023) >> 2;
    axc[kq] = ((ca & 3) * 8) ^ ((((ca & 1023) >> 4) & 3) << 3);
  }
  int brr[2], bxc[2];                           // B: 1024 chunks, 2/thread (kh = kq)
  #pragma unroll
  for (int kq = 0; kq < 2; ++kq) {
    int cb = tid + kq * 512;
    brr[kq] = (cb & 511) >> 2;
    bxc[kq] = ((cb & 3) * 8) ^ ((((cb & 511) >> 4) & 3) << 3);
  }

#define STAGE(buf, kb) do { \
    unsigned short* da_ = lds + (buf) * 16384; \
    _Pragma("unroll") \
    for (int kq = 0; kq < 4; ++kq) { \
      int ca_ = tid + kq * 512; \
      gld_lds16(Ab + (size_t)ar[kq] * 2048 + (kb) + (ca_ >> 10) * 32 + axc[kq], da_ + ca_ * 8); \
    } \
    unsigned short* db_ = lds + 32768 + (buf) * 8192; \
    _Pragma("unroll") \
    for (int kq = 0; kq < 2; ++kq) { \
      int cb_ = tid + kq * 512; \
      gld_lds16(Bb + (size_t)brr[kq] * 2048 + (kb) + kq * 32 + bxc[kq], db_ + cb_ * 8); \
    } \
  } while (0)

  f32x4 acc[4][4] = {};

  STAGE(0, 0);
  __syncthreads();

  const unsigned short* aB = lds + (wr * 64 + l16) * 32 + (quad * 8 ^ swz);
  const unsigned short* bB = lds + 32768 + (wc * 64 + l16) * 32 + (quad * 8 ^ swz);

  for (int t = 0; t < 32; ++t) {
    const int cur = t & 1;
    if (t < 31) STAGE(cur ^ 1, (t + 1) * 64);
    #pragma unroll
    for (int kh = 0; kh < 2; ++kh) {
      bf16x8 a[4], b[4];
      #pragma unroll
      for (int m = 0; m < 4; ++m)
        a[m] = *(const bf16x8*)(aB + cur * 16384 + kh * 8192 + m * 512);
      #pragma unroll
      for (int n = 0; n < 4; ++n)
        b[n] = *(const bf16x8*)(bB + cur * 8192 + kh * 4096 + n * 512);
      #pragma unroll
      for (int m = 0; m < 4; ++m)
        #pragma unroll
        for (int n = 0; n < 4; ++n)
          acc[m][n] = __builtin_amdgcn_mfma_f32_16x16x32_bf16(a[m], b[n], acc[m][n], 0, 0, 0);
    }
    __syncthreads();
  }
#undef STAGE

  #pragma unroll
  for (int m = 0; m < 4; ++m)
    #pragma unroll
    for (int r = 0; r < 4; ++r) {
      int row = m0 + wr * 64 + m * 16 + quad * 4 + r;
      #pragma unroll
      for (int n = 0; n < 4; ++n) {
        int col = n0 + wc * 64 + n * 16 + l16;
        out[(size_t)row * 2048 + col] = acc[m][n][r];
      }
    }
}

// ---------------- RoPE + RMSNorm row helper ----------------
template <int NH>
__device__ __forceinline__ void ropenorm_row(
    const unsigned short* __restrict__ in, const float* __restrict__ cs,
    const float* __restrict__ sn, unsigned short* __restrict__ out,
    float oscale, int off, int row, int lane) {
  int head = row % NH;
  int t = (row / NH) & (T_ - 1);
  int b = row / (NH * T_);
  const unsigned short* p = in + (size_t)(b * T_ + t) * 3072 + off + head * D_;
  unsigned int u  = *(const unsigned int*)(p + 2 * lane);
  unsigned int up = (unsigned int)__shfl_xor((int)u, 32, 64);
  int dh = (lane & 31) * 2;
  float2 c2 = ((const float2*)(cs + t * 64))[lane & 31];
  float2 s2 = ((const float2*)(sn + t * 64))[lane & 31];
  float a0 = b2f((unsigned short)(u & 0xffff)),  a1 = b2f((unsigned short)(u >> 16));
  float p0 = b2f((unsigned short)(up & 0xffff)), p1 = b2f((unsigned short)(up >> 16));
  float sgn = (lane < 32) ? 1.0f : -1.0f;
  float oa = a0 * c2.x + sgn * p0 * s2.x;
  float ob = a1 * c2.y + sgn * p1 * s2.y;
  float ss = oa * oa + ob * ob;
  #pragma unroll
  for (int off2 = 32; off2 > 0; off2 >>= 1) ss += __shfl_xor(ss, off2, 64);
  float r = rsqrtf(ss * (1.0f / 128.0f) + 1.1920929e-07f) * oscale;
  unsigned int outu = cvt_pk_bf16(oa * r, ob * r);
  size_t base = ((size_t)((b * NH + head) * 128 + (t >> 4))) * 2048 + (size_t)(t & 15) * 8;
  int f = ((lane < 32) ? 0 : 8) + (dh >> 3);
  *(unsigned int*)(out + base + (size_t)f * 128 + (dh & 7)) = outu;
}

// ------- post: RoPE+RMSNorm for Q (16384 blk) + K (4096 blk) + V repack (256 blk) -------
__global__ void post_k(const unsigned short* __restrict__ qkv,
                       const float* __restrict__ cs, const float* __restrict__ sn,
                       unsigned short* __restrict__ qfr, unsigned short* __restrict__ kfr,
                       unsigned short* __restrict__ vf) {
  int bid = blockIdx.x, tid = threadIdx.x;
  int lane = tid & 63, wv = tid >> 6;
  if (bid < 16384) {
    ropenorm_row<16>(qkv, cs, sn, qfr, 0.08838834764831845f, 0, bid * 4 + wv, lane);
    return;
  }
  if (bid < 20480) {
    ropenorm_row<4>(qkv, cs, sn, kfr, 1.0f, 2048, (bid - 16384) * 4 + wv, lane);
    return;
  }
  // V repack: per (b,kv): [it 32][dt = d>>4 (8)][f (8)][d&15 (16)][t&7 (8)]
  int id = bid - 20480;                      // 0..255
  int it = id & 31, y = id >> 5;
  int b = y >> 2, kv = y & 3;
  int d = tid & 127, ty = tid >> 7;
  int t0 = it * 64;
  size_t obase = ((size_t)((b * KV_ + kv) * 32 + it)) * 8192
               + (size_t)(d >> 4) * 1024 + (size_t)(d & 15) * 8;
  #pragma unroll
  for (int tcg = 0; tcg < 4; ++tcg) {
    int tc = ty * 4 + tcg;                   // f chunk 0..7
    unsigned short val[8];
    #pragma unroll
    for (int e = 0; e < 8; ++e)              // coalesced: 128 lanes contiguous in d
      val[e] = qkv[((size_t)(b * T_) + t0 + tc * 8 + e) * 3072 + 2560 + kv * D_ + d];
    ushort4 u0 = {val[0], val[1], val[2], val[3]};
    ushort4 u1 = {val[4], val[5], val[6], val[7]};
    *(ushort4*)(vf + obase + (size_t)tc * 128)     = u0;
    *(ushort4*)(vf + obase + (size_t)tc * 128 + 4) = u1;
  }
}

// ------------ flash attention v13: q-split 2-block/CU, no combine ------------
// v11 (56us) limiter: 8 waves lockstep in ONE 133KB-LDS block/CU — 3 block-wide
// barriers/round with nothing co-resident to hide them, plus an LDS combine epilogue.
// v13: block = 4 waves (4 heads) owning 16 q-rows (sub half of a q-tile); walks ALL its
// kv tiles -> NO cross-wave combine. LDS 58KB (K 2x16 dbuf | V 16 | P 4x2.25KB) ->
// 2 blocks/CU: one block's MFMA fills the other's barrier/vmcnt stalls; barriers sync
// only 4 waves. Uniform work: grid (8,64), y=(j,sub); phases qt=j then 63-j -> every
// block exactly 33 rounds. Cost: K/V staged per 16-row block (L2 traffic x2, absorbed
// at 16% L2 util). Counted vmcnt (4 loads/stage): steady 12 -> vmcnt(8) K landed ->
// vmcnt(4) V landed; tail 8->4->0; Q-loads/epilogue stores only make waits conservative.
// Swizzle: content[d]=src[d^(((d>>7)&3)<<4)]; reader logical addr bits7-8 = quad for
// both K and V paths -> read^(quad<<4) recovers src (same scheme verified R6-R11).
__global__ __launch_bounds__(256, 2) void attn_kernel(
    const unsigned short* __restrict__ qf, const unsigned short* __restrict__ kf,
    const unsigned short* __restrict__ vf, unsigned short* __restrict__ yb) {
  __shared__ __align__(16) char smem[58368];
  unsigned short* kls = (unsigned short*)smem;            // [2 buf][8192 sh] = 32KB
  unsigned short* vls = (unsigned short*)(smem + 32768);  // [8192 sh] = 16KB
  unsigned short* Pls = (unsigned short*)(smem + 49152);  // 4 waves x 16x72 sh = 9216B

  const int xp = (int)blockIdx.x, b = xp >> 2, kv = xp & 3;   // XCD swizzle: id%8 = xp
  const int yp = (int)blockIdx.y;                             // 0..63
  const int j = yp >> 1, sub = yp & 1;
  const int tid = (int)threadIdx.x;                           // 0..255
  const int w = tid >> 6, lane = tid & 63;
  const int quad = lane >> 4, l16 = lane & 15;
  const int h = kv * 4 + w;
  unsigned short* myP = Pls + w * (16 * 72);

  const unsigned short* Kf = kf + (size_t)(b * KV_ + kv) * 128 * 2048;
  const unsigned short* Vf = vf + (size_t)(b * KV_ + kv) * 32 * 8192;

  const int swl = quad << 4;                 // swizzle key (shorts)

#define STAGE_K(buf, it0) do { \
    const unsigned short* s_ = Kf + (size_t)(it0) * 8192; \
    unsigned short* d_ = kls + (buf) * 8192; \
    _Pragma("unroll") \
    for (int q_ = 0; q_ < 4; ++q_) \
      gld_lds16(s_ + ((tid * 8 + q_ * 2048) ^ swl), d_ + tid * 8 + q_ * 2048); \
  } while (0)
#define STAGE_V(it0) do { \
    const unsigned short* s_ = Vf + (size_t)(it0) * 8192; \
    _Pragma("unroll") \
    for (int q_ = 0; q_ < 4; ++q_) \
      gld_lds16(s_ + ((tid * 8 + q_ * 2048) ^ swl), vls + tid * 8 + q_ * 2048); \
  } while (0)

  for (int ph = 0; ph < 2; ++ph) {
    const int qt = ph ? (63 - j) : j;
    const int q0 = qt * 32 + sub * 16;
    const int ntile = (qt >> 1) + 1;

    // persistent Q fragments: one 16-row B-operand (t16 tile = qt*2+sub)
    const unsigned short* Qf = qf + ((size_t)(b * H_ + h) * 128 + qt * 2 + sub) * 2048;
    bf16x8 bq[4];
    #pragma unroll
    for (int kk = 0; kk < 4; ++kk)
      bq[kk] = *(const bf16x8*)(Qf + (kk * 4 + quad) * 128 + l16 * 8);

    float l_i = 0.f;
    f32x4 o[8] = {};

    STAGE_K(0, 0);                           // prologue: K tile 0 -> buf 0

    for (int r = 0; r < ntile; ++r) {
      const int cur = r & 1;
      const bool more = (r + 1 < ntile);
      STAGE_V(r);
      if (more) STAGE_K(cur ^ 1, r + 1);
      if (more) asm volatile("s_waitcnt vmcnt(8)" ::: "memory");  // K(r) landed (own)
      else      asm volatile("s_waitcnt vmcnt(4)" ::: "memory");
      __builtin_amdgcn_s_barrier();                               // ...and block-wide

      // S^T = K Q^T : 64 k rows x 16 q cols
      f32x4 sc[4] = {};
      const unsigned short* kb = kls + cur * 8192;
      #pragma unroll
      for (int kk = 0; kk < 4; ++kk) {
        bf16x8 ak[4];
        #pragma unroll
        for (int jt = 0; jt < 4; ++jt)
          ak[jt] = *(const bf16x8*)(kb + ((jt * 2048 + (kk * 4 + quad) * 128 + l16 * 8) ^ swl));
        #pragma unroll
        for (int jt = 0; jt < 4; ++jt)
          sc[jt] = __builtin_amdgcn_mfma_f32_16x16x32_bf16(ak[jt], bq[kk], sc[jt], 0, 0, 0);
      }
      if (r == ntile - 1) {                  // causal mask on the diagonal tile
        #pragma unroll
        for (int jt = 0; jt < 4; ++jt) {
          int kg = r * 64 + jt * 16 + quad * 4;
          int qg = q0 + l16;
          #pragma unroll
          for (int rr = 0; rr < 4; ++rr)
            if (kg + rr > qg) sc[jt][rr] = -3.0e38f;
        }
      }
      // static-max softmax: p = exp(s - 12); per-lane l partial (q = l16)
      float part = 0.f;
      #pragma unroll
      for (int jt = 0; jt < 4; ++jt)
        #pragma unroll
        for (int rr = 0; rr < 4; ++rr) {
          float p = __expf(sc[jt][rr] - 12.0f);
          sc[jt][rr] = p; part += p;
        }
      l_i += part;
      // P^T (C-layout) -> private LDS row-major P [q16][k64]
      #pragma unroll
      for (int jt = 0; jt < 4; ++jt) {
        uint2 uu;
        uu.x = cvt_pk_bf16(sc[jt][0], sc[jt][1]);
        uu.y = cvt_pk_bf16(sc[jt][2], sc[jt][3]);
        *(uint2*)(myP + l16 * 72 + jt * 16 + quad * 4) = uu;
      }

      if (more) asm volatile("s_waitcnt vmcnt(4)" ::: "memory");  // V(r) landed
      else      asm volatile("s_waitcnt vmcnt(0)" ::: "memory");
      __builtin_amdgcn_s_barrier();

      // O += P V
      #pragma unroll
      for (int kk2 = 0; kk2 < 2; ++kk2) {
        bf16x8 ap = *(const bf16x8*)(myP + l16 * 72 + kk2 * 32 + quad * 8);
        bf16x8 bv2[8];
        #pragma unroll
        for (int jj = 0; jj < 8; ++jj)
          bv2[jj] = *(const bf16x8*)(vls + ((jj * 1024 + (kk2 * 4 + quad) * 128 + l16 * 8) ^ swl));
        #pragma unroll
        for (int jj = 0; jj < 8; ++jj)
          o[jj] = __builtin_amdgcn_mfma_f32_16x16x32_bf16(ap, bv2[jj], o[jj], 0, 0, 0);
      }
      __builtin_amdgcn_s_barrier();          // all PV reads done before next STAGE_V
    }

    // epilogue: reduce l across quads, normalize, store (no cross-wave combine)
    float l = l_i;
    l += __shfl_xor(l, 16, 64);
    l += __shfl_xor(l, 32, 64);
    float linv = 1.0f / l;
    float lr[4];
    #pragma unroll
    for (int rr = 0; rr < 4; ++rr) lr[rr] = __shfl(linv, quad * 4 + rr, 64);
    #pragma unroll
    for (int rr = 0; rr < 4; ++rr) {
      int tg = q0 + quad * 4 + rr;
      unsigned short* yr = yb + (((size_t)(b * T_ + tg)) * H_ + h) * D_;
      #pragma unroll
      for (int jj = 0; jj < 8; ++jj)
        yr[jj * 16 + l16] = f2b(o[jj][rr] * lr[rr]);
    }
    // next phase's STAGE_K is safe: all waves passed the last round's barrier #3,
    // so every kls/vls read of this phase has completed.
  }
#undef STAGE_K
#undef STAGE_V
}

extern "C" void kernel_launch(void* const* d_in, const int* in_sizes, int n_in,
                              void* d_out, int out_size, void* d_ws, size_t ws_size,
                              hipStream_t stream) {
  (void)in_sizes; (void)n_in; (void)out_size; (void)ws_size;
  const float* x  = (const float*)d_in[0];
  const float* cs = (const float*)d_in[1];
  const float* sn = (const float*)d_in[2];
  const float* Wq = (const float*)d_in[3];
  const float* Wk = (const float*)d_in[4];
  const float* Wv = (const float*)d_in[5];
  const float* Wo = (const float*)d_in[6];
  float* out = (float*)d_out;
  char* ws = (char*)d_ws;

  // workspace layout (bytes); regions reused across phases. total ~88MB.
  unsigned short* xb     = (unsigned short*)(ws + 0);          // 4096x2048 bf16 (dead after qkv)
  unsigned short* Wqkvt  = (unsigned short*)(ws + 16777216);   // 3072x2048 bf16 (dead after qkv)
  unsigned short* Wot    = (unsigned short*)(ws + 29360128);   // needed until out_gemm
  unsigned short* qkvcat = (unsigned short*)(ws + 37748736);   // 4096x3072 bf16 fused Q|K|V
  unsigned short* qfr    = (unsigned short*)(ws + 62914560);   // Q frag order
  unsigned short* kfr    = (unsigned short*)(ws + 79691776);   // K frag order
  unsigned short* vfr    = (unsigned short*)(ws + 83886080);   // V frag order
  unsigned short* yb     = xb;                                 // attn out (B,T,C) bf16 (xb dead)

  prep<<<dim3(18432), dim3(256), 0, stream>>>(
      x, xb, Wq, Wk, Wv, Wo,
      Wqkvt, Wqkvt + (size_t)2048 * 2048, Wqkvt + (size_t)2560 * 2048, Wot);
  qkv_gemm2p<<<dim3(256), dim3(512), 0, stream>>>(xb, Wqkvt, qkvcat);
  post_k<<<dim3(20736), dim3(256), 0, stream>>>(qkvcat, cs, sn, qfr, kfr, vfr);
  attn_kernel<<<dim3(8, 64), dim3(256), 0, stream>>>(qfr, kfr, vfr, yb);
  out_gemm2p<<<dim3(256), dim3(512), 0, stream>>>(yb, Wot, out);
}